// Round 1
// baseline (1850.626 us; speedup 1.0000x reference)
//
#include <hip/hip_runtime.h>
#include <hip/hip_bf16.h>

#define Tn 8192
#define Dn 1024
#define Fn 4096
#define SHn 2048
#define En 16
#define CAPn 1024

typedef __bf16 bf16_t;
typedef bf16_t bf16x8 __attribute__((ext_vector_type(8)));
typedef float f32x4 __attribute__((ext_vector_type(4)));

__device__ __forceinline__ unsigned short f2bf(float f) {
  unsigned int u = __builtin_bit_cast(unsigned int, f);
  u += 0x7FFFu + ((u >> 16) & 1u);
  return (unsigned short)(u >> 16);
}
__device__ __forceinline__ unsigned int pack2(float a, float b) {
  return (unsigned int)f2bf(a) | ((unsigned int)f2bf(b) << 16);
}

// ---------------- x fp32 -> bf16 ----------------
__global__ __launch_bounds__(256) void kconvert(const float* __restrict__ x,
                                                unsigned short* __restrict__ xb) {
  int i = blockIdx.x * 256 + threadIdx.x;  // one 8-elem chunk per thread
  const float4* src = (const float4*)x;
  float4 a = src[2 * i], b = src[2 * i + 1];
  uint4 u = { pack2(a.x, a.y), pack2(a.z, a.w), pack2(b.x, b.y), pack2(b.z, b.w) };
  ((uint4*)xb)[i] = u;
}

// ---------------- gate scores: sigmoid(x @ gate_w^T), stored [E][T] ----------------
__global__ __launch_bounds__(256) void kscores(const float* __restrict__ x,
                                               const float* __restrict__ gw,
                                               float* __restrict__ sc) {
  __shared__ float sx[Dn];
  int tid = threadIdx.x, tok = blockIdx.x;
  ((float4*)sx)[tid] = ((const float4*)(x + (size_t)tok * Dn))[tid];
  __syncthreads();
  int e = tid >> 4, kl = tid & 15;
  const float4* w = (const float4*)(gw + e * Dn);
  const float4* xv = (const float4*)sx;
  float acc = 0.f;
#pragma unroll
  for (int j = 0; j < 16; ++j) {
    float4 a = w[kl + 16 * j], b = xv[kl + 16 * j];
    acc += a.x * b.x + a.y * b.y + a.z * b.z + a.w * b.w;
  }
#pragma unroll
  for (int off = 8; off; off >>= 1) acc += __shfl_xor(acc, off, 64);
  if (kl == 0) sc[(size_t)e * Tn + tok] = 1.f / (1.f + expf(-acc));
}

// ---------------- per-expert top-CAP radix select (ties: lowest index, = jax top_k) ----------------
__global__ __launch_bounds__(256) void kselect(const float* __restrict__ scores,
                                               int* __restrict__ ids,
                                               float* __restrict__ oscore) {
  __shared__ unsigned int keys[Tn];   // 32KB; scores > 0 so uint order == float order
  __shared__ unsigned int hist[256];
  __shared__ unsigned int sh_prefix, sh_k, sh_cnt, sh_eq;
  __shared__ int eqlist[1024];
  const int tid = threadIdx.x, e = blockIdx.x;
  const float* row = scores + (size_t)e * Tn;
  for (int i = 0; i < Tn / 256; ++i)
    keys[tid + i * 256] = __float_as_uint(row[tid + i * 256]);
  if (tid == 0) { sh_prefix = 0u; sh_k = CAPn; }
  __syncthreads();
  for (int shift = 24; shift >= 0; shift -= 8) {
    hist[tid] = 0u;
    __syncthreads();
    unsigned int prefix = sh_prefix;
    unsigned int mask = (shift == 24) ? 0u : (0xFFFFFFFFu << (shift + 8));
    for (int i = 0; i < Tn / 256; ++i) {
      unsigned int kk = keys[tid + i * 256];
      if ((kk & mask) == prefix) atomicAdd(&hist[(kk >> shift) & 255], 1u);
    }
    __syncthreads();
    if (tid == 0) {
      unsigned int k = sh_k, c = 0; int b;
      for (b = 255; b >= 0; --b) { c += hist[b]; if (c >= k) break; }
      sh_k = k - (c - hist[b]);
      sh_prefix = prefix | ((unsigned int)b << shift);
    }
    __syncthreads();
  }
  const unsigned int thr = sh_prefix;
  if (tid == 0) { sh_cnt = 0u; sh_eq = 0u; }
  __syncthreads();
  const int base = e * CAPn;
  for (int i = 0; i < Tn / 256; ++i) {
    int t = tid + i * 256;
    unsigned int kk = keys[t];
    if (kk > thr) {
      unsigned int p = atomicAdd(&sh_cnt, 1u);
      ids[base + p] = t;
      oscore[base + p] = __uint_as_float(kk);
    } else if (kk == thr) {
      unsigned int p = atomicAdd(&sh_eq, 1u);
      if (p < 1024u) eqlist[p] = t;
    }
  }
  __syncthreads();
  if (tid == 0) {
    int need = CAPn - (int)sh_cnt;
    int m = (int)sh_eq; if (m > 1024) m = 1024;
    for (int j = 0; j < need; ++j) {
      int best = 1 << 30, bi = 0;
      for (int i2 = 0; i2 < m; ++i2)
        if (eqlist[i2] < best) { best = eqlist[i2]; bi = i2; }
      eqlist[bi] = 1 << 30;
      ids[base + (int)sh_cnt + j] = best;
      oscore[base + (int)sh_cnt + j] = __uint_as_float(thr);
    }
  }
}

// ---------------- GLU GEMM: H = bf16( silu(A@Wg^T + bg) * (A@Wu^T + bu) ) ----------------
// grid: (M/128, N/128, Z). A rows gathered via idsg when non-null. K = Dn.
__global__ __launch_bounds__(256, 2) void kglu(
    const unsigned short* __restrict__ X, const int* __restrict__ idsg,
    const float* __restrict__ Wg, const float* __restrict__ Wu,
    const float* __restrict__ biasg, const float* __restrict__ biasu,
    unsigned short* __restrict__ H, int N, int Mz) {
  constexpr int K = Dn;
  const int tid = threadIdx.x;
  const int bm = blockIdx.x, bn = blockIdx.y, z = blockIdx.z;
  const int lane = tid & 63, wid = tid >> 6;
  const int wm = wid >> 1, wn = wid & 1;
  const int lrow = lane & 15, lk = lane >> 4;

  __shared__ alignas(16) unsigned char sA[16384];
  __shared__ alignas(16) unsigned char sB1[16384];
  __shared__ alignas(16) unsigned char sB2[16384];
  __shared__ int sIds[128];

  const int row0 = bm * 128;
  if (tid < 128) sIds[tid] = idsg ? idsg[z * CAPn + row0 + tid] : (row0 + tid);

  const float* wgp = Wg + (size_t)z * N * K;
  const float* wup = Wu + (size_t)z * N * K;

  f32x4 accG[4][4], accU[4][4];
#pragma unroll
  for (int m = 0; m < 4; ++m)
#pragma unroll
    for (int n = 0; n < 4; ++n) {
      accG[m][n] = {0.f, 0.f, 0.f, 0.f};
      accU[m][n] = {0.f, 0.f, 0.f, 0.f};
    }

  for (int k0 = 0; k0 < K; k0 += 64) {
    __syncthreads();
#pragma unroll
    for (int i = 0; i < 4; ++i) {
      int c = tid + i * 256;
      int r = c >> 3, ch = c & 7;
      int dst = r * 128 + ((ch ^ (r & 7)) << 4);
      uint4 va = *(const uint4*)(X + (size_t)sIds[r] * K + (k0 + ch * 8));
      *(uint4*)(sA + dst) = va;
      const float* pg = wgp + (size_t)(bn * 128 + r) * K + (k0 + ch * 8);
      float4 g0 = *(const float4*)pg, g1 = *(const float4*)(pg + 4);
      uint4 ug = { pack2(g0.x, g0.y), pack2(g0.z, g0.w), pack2(g1.x, g1.y), pack2(g1.z, g1.w) };
      *(uint4*)(sB1 + dst) = ug;
      const float* pu = wup + (size_t)(bn * 128 + r) * K + (k0 + ch * 8);
      float4 u0 = *(const float4*)pu, u1 = *(const float4*)(pu + 4);
      uint4 uu = { pack2(u0.x, u0.y), pack2(u0.z, u0.w), pack2(u1.x, u1.y), pack2(u1.z, u1.w) };
      *(uint4*)(sB2 + dst) = uu;
    }
    __syncthreads();
#pragma unroll
    for (int ks = 0; ks < 2; ++ks) {
      const int sw = ((ks * 4 + lk) ^ (lrow & 7)) << 4;
      bf16x8 av[4], gv[4], uv[4];
#pragma unroll
      for (int m = 0; m < 4; ++m)
        av[m] = *(const bf16x8*)(sA + (wm * 64 + m * 16 + lrow) * 128 + sw);
#pragma unroll
      for (int n = 0; n < 4; ++n) {
        gv[n] = *(const bf16x8*)(sB1 + (wn * 64 + n * 16 + lrow) * 128 + sw);
        uv[n] = *(const bf16x8*)(sB2 + (wn * 64 + n * 16 + lrow) * 128 + sw);
      }
#pragma unroll
      for (int m = 0; m < 4; ++m)
#pragma unroll
        for (int n = 0; n < 4; ++n) {
          accG[m][n] = __builtin_amdgcn_mfma_f32_16x16x32_bf16(av[m], gv[n], accG[m][n], 0, 0, 0);
          accU[m][n] = __builtin_amdgcn_mfma_f32_16x16x32_bf16(av[m], uv[n], accU[m][n], 0, 0, 0);
        }
    }
  }
#pragma unroll
  for (int n = 0; n < 4; ++n) {
    int col = bn * 128 + wn * 64 + n * 16 + lrow;
    float bg = biasg ? biasg[(size_t)z * N + col] : 0.f;
    float bu = biasu ? biasu[(size_t)z * N + col] : 0.f;
#pragma unroll
    for (int m = 0; m < 4; ++m) {
#pragma unroll
      for (int j = 0; j < 4; ++j) {
        float g = accG[m][n][j] + bg;
        float u = accU[m][n][j] + bu;
        float h = g / (1.f + __expf(-g)) * u;
        int row = row0 + wm * 64 + m * 16 + lk * 4 + j;
        H[(size_t)z * Mz * N + (size_t)row * N + col] = f2bf(h);
      }
    }
  }
}

// ---------------- down GEMM: Out = A@W^T (+bias, xscore scatter-add for experts) ----------------
// grid: (Mz/128, Dn/128, Z)
template <int K>
__global__ __launch_bounds__(256, 2) void kdown(
    const unsigned short* __restrict__ Hin, const float* __restrict__ W,
    const float* __restrict__ bias, const int* __restrict__ idsg,
    const float* __restrict__ scg, float* __restrict__ Out, int Mz) {
  constexpr int N = Dn;
  const int tid = threadIdx.x;
  const int bm = blockIdx.x, bn = blockIdx.y, z = blockIdx.z;
  const int lane = tid & 63, wid = tid >> 6;
  const int wm = wid >> 1, wn = wid & 1;
  const int lrow = lane & 15, lk = lane >> 4;

  __shared__ alignas(16) unsigned char sA[16384];
  __shared__ alignas(16) unsigned char sB[16384];
  __shared__ int sIds[128];
  __shared__ float sSc[128];

  const int row0 = bm * 128;
  if (idsg && tid < 128) {
    sIds[tid] = idsg[z * CAPn + row0 + tid];
    sSc[tid] = scg[z * CAPn + row0 + tid];
  }
  const unsigned short* A = Hin + (size_t)z * Mz * K;
  const float* wp = W + (size_t)z * N * K;

  f32x4 acc[4][4];
#pragma unroll
  for (int m = 0; m < 4; ++m)
#pragma unroll
    for (int n = 0; n < 4; ++n) acc[m][n] = {0.f, 0.f, 0.f, 0.f};

  for (int k0 = 0; k0 < K; k0 += 64) {
    __syncthreads();
#pragma unroll
    for (int i = 0; i < 4; ++i) {
      int c = tid + i * 256;
      int r = c >> 3, ch = c & 7;
      int dst = r * 128 + ((ch ^ (r & 7)) << 4);
      uint4 va = *(const uint4*)(A + (size_t)(row0 + r) * K + (k0 + ch * 8));
      *(uint4*)(sA + dst) = va;
      const float* pb = wp + (size_t)(bn * 128 + r) * K + (k0 + ch * 8);
      float4 b0 = *(const float4*)pb, b1 = *(const float4*)(pb + 4);
      uint4 ub = { pack2(b0.x, b0.y), pack2(b0.z, b0.w), pack2(b1.x, b1.y), pack2(b1.z, b1.w) };
      *(uint4*)(sB + dst) = ub;
    }
    __syncthreads();
#pragma unroll
    for (int ks = 0; ks < 2; ++ks) {
      const int sw = ((ks * 4 + lk) ^ (lrow & 7)) << 4;
      bf16x8 av[4], bv[4];
#pragma unroll
      for (int m = 0; m < 4; ++m)
        av[m] = *(const bf16x8*)(sA + (wm * 64 + m * 16 + lrow) * 128 + sw);
#pragma unroll
      for (int n = 0; n < 4; ++n)
        bv[n] = *(const bf16x8*)(sB + (wn * 64 + n * 16 + lrow) * 128 + sw);
#pragma unroll
      for (int m = 0; m < 4; ++m)
#pragma unroll
        for (int n = 0; n < 4; ++n)
          acc[m][n] = __builtin_amdgcn_mfma_f32_16x16x32_bf16(av[m], bv[n], acc[m][n], 0, 0, 0);
    }
  }
#pragma unroll
  for (int n = 0; n < 4; ++n) {
    int col = bn * 128 + wn * 64 + n * 16 + lrow;
    float bvv = bias ? bias[(size_t)z * N + col] : 0.f;
#pragma unroll
    for (int m = 0; m < 4; ++m) {
#pragma unroll
      for (int j = 0; j < 4; ++j) {
        int rl = wm * 64 + m * 16 + lk * 4 + j;
        float v = acc[m][n][j] + bvv;
        if (idsg) {
          atomicAdd(Out + (size_t)sIds[rl] * Dn + col, sSc[rl] * v);
        } else {
          Out[(size_t)(row0 + rl) * Dn + col] = v;
        }
      }
    }
  }
}

extern "C" void kernel_launch(void* const* d_in, const int* in_sizes, int n_in,
                              void* d_out, int out_size, void* d_ws, size_t ws_size,
                              hipStream_t stream) {
  const float* x      = (const float*)d_in[0];
  const float* gate_w = (const float*)d_in[1];
  const float* up_w   = (const float*)d_in[2];
  const float* up_b   = (const float*)d_in[3];
  const float* gw     = (const float*)d_in[4];
  const float* gb     = (const float*)d_in[5];
  const float* down_w = (const float*)d_in[6];
  const float* down_b = (const float*)d_in[7];
  const float* shg    = (const float*)d_in[8];
  const float* shu    = (const float*)d_in[9];
  const float* shd    = (const float*)d_in[10];
  float* out = (float*)d_out;

  // workspace layout
  const size_t H_BYTES   = (size_t)En * CAPn * Fn * 2;      // 134217728
  const size_t XB_BYTES  = (size_t)Tn * Dn * 2;             // 16777216
  const size_t SC_BYTES  = (size_t)En * Tn * 4;             // 524288
  const size_t ID_BYTES  = (size_t)En * CAPn * 4;           // 65536
  const size_t need = H_BYTES + XB_BYTES + SC_BYTES + 2 * ID_BYTES;
  if (ws_size < need) return;  // workspace too small — fail cleanly

  char* ws = (char*)d_ws;
  unsigned short* H  = (unsigned short*)ws;
  unsigned short* xb = (unsigned short*)(ws + H_BYTES);
  float* scores      = (float*)(ws + H_BYTES + XB_BYTES);
  int* ids           = (int*)(ws + H_BYTES + XB_BYTES + SC_BYTES);
  float* osc         = (float*)(ws + H_BYTES + XB_BYTES + SC_BYTES + ID_BYTES);

  kconvert<<<Tn * Dn / 8 / 256, 256, 0, stream>>>(x, xb);
  kscores<<<Tn, 256, 0, stream>>>(x, gate_w, scores);
  kselect<<<En, 256, 0, stream>>>(scores, ids, osc);

  // shared dense GLU MLP first (writes every element of d_out)
  kglu<<<dim3(Tn / 128, SHn / 128, 1), 256, 0, stream>>>(
      xb, nullptr, shg, shu, nullptr, nullptr, H, SHn, Tn);
  kdown<SHn><<<dim3(Tn / 128, Dn / 128, 1), 256, 0, stream>>>(
      H, shd, nullptr, nullptr, nullptr, out, Tn);

  // expert path (atomic scatter-add on top)
  kglu<<<dim3(CAPn / 128, Fn / 128, En), 256, 0, stream>>>(
      xb, ids, gw, up_w, gb, up_b, H, Fn, CAPn);
  kdown<Fn><<<dim3(CAPn / 128, Dn / 128, En), 256, 0, stream>>>(
      H, down_w, down_b, ids, osc, out, CAPn);
}

// Round 2
// 959.093 us; speedup vs baseline: 1.9296x; 1.9296x over previous
//
#include <hip/hip_runtime.h>
#include <hip/hip_bf16.h>

#define Tn 8192
#define Dn 1024
#define Fn 4096
#define SHn 2048
#define En 16
#define CAPn 1024

typedef __bf16 bf16_t;
typedef bf16_t bf16x8 __attribute__((ext_vector_type(8)));
typedef float f32x4 __attribute__((ext_vector_type(4)));

__device__ __forceinline__ unsigned short f2bf(float f) {
  unsigned int u = __builtin_bit_cast(unsigned int, f);
  u += 0x7FFFu + ((u >> 16) & 1u);
  return (unsigned short)(u >> 16);
}
__device__ __forceinline__ unsigned int pack2(float a, float b) {
  return (unsigned int)f2bf(a) | ((unsigned int)f2bf(b) << 16);
}

__device__ __forceinline__ void gload16(const void* g, void* l) {
  __builtin_amdgcn_global_load_lds(
      (const __attribute__((address_space(1))) unsigned int*)g,
      (__attribute__((address_space(3))) unsigned int*)l, 16, 0, 0);
}

// ---------------- fp32 -> bf16 convert (grid-stride, 8 elems/thread/iter) ----------------
__global__ __launch_bounds__(256) void kcvt(const float* __restrict__ s,
                                            unsigned short* __restrict__ d, int n8) {
  int i = blockIdx.x * 256 + threadIdx.x;
  int stride = gridDim.x * 256;
  const float4* sv = (const float4*)s;
  for (; i < n8; i += stride) {
    float4 a = sv[2 * i], b = sv[2 * i + 1];
    uint4 u = { pack2(a.x, a.y), pack2(a.z, a.w), pack2(b.x, b.y), pack2(b.z, b.w) };
    ((uint4*)d)[i] = u;
  }
}

// ---------------- gate scores: sigmoid(x @ gate_w^T), stored [E][T] ----------------
__global__ __launch_bounds__(256) void kscores(const float* __restrict__ x,
                                               const float* __restrict__ gw,
                                               float* __restrict__ sc) {
  __shared__ float sx[Dn];
  int tid = threadIdx.x, tok = blockIdx.x;
  ((float4*)sx)[tid] = ((const float4*)(x + (size_t)tok * Dn))[tid];
  __syncthreads();
  int e = tid >> 4, kl = tid & 15;
  const float4* w = (const float4*)(gw + e * Dn);
  const float4* xv = (const float4*)sx;
  float acc = 0.f;
#pragma unroll
  for (int j = 0; j < 16; ++j) {
    float4 a = w[kl + 16 * j], b = xv[kl + 16 * j];
    acc += a.x * b.x + a.y * b.y + a.z * b.z + a.w * b.w;
  }
#pragma unroll
  for (int off = 8; off; off >>= 1) acc += __shfl_xor(acc, off, 64);
  if (kl == 0) sc[(size_t)e * Tn + tok] = 1.f / (1.f + expf(-acc));
}

// ---------------- per-expert top-CAP radix select (ties: lowest index) ----------------
__global__ __launch_bounds__(256) void kselect(const float* __restrict__ scores,
                                               int* __restrict__ ids,
                                               float* __restrict__ oscore) {
  __shared__ unsigned int keys[Tn];
  __shared__ unsigned int hist[256];
  __shared__ unsigned int sh_prefix, sh_k, sh_cnt, sh_eq;
  __shared__ int eqlist[1024];
  const int tid = threadIdx.x, e = blockIdx.x;
  const float* row = scores + (size_t)e * Tn;
  for (int i = 0; i < Tn / 256; ++i)
    keys[tid + i * 256] = __float_as_uint(row[tid + i * 256]);
  if (tid == 0) { sh_prefix = 0u; sh_k = CAPn; }
  __syncthreads();
  for (int shift = 24; shift >= 0; shift -= 8) {
    hist[tid] = 0u;
    __syncthreads();
    unsigned int prefix = sh_prefix;
    unsigned int mask = (shift == 24) ? 0u : (0xFFFFFFFFu << (shift + 8));
    for (int i = 0; i < Tn / 256; ++i) {
      unsigned int kk = keys[tid + i * 256];
      if ((kk & mask) == prefix) atomicAdd(&hist[(kk >> shift) & 255], 1u);
    }
    __syncthreads();
    if (tid == 0) {
      unsigned int k = sh_k, c = 0; int b;
      for (b = 255; b >= 0; --b) { c += hist[b]; if (c >= k) break; }
      sh_k = k - (c - hist[b]);
      sh_prefix = prefix | ((unsigned int)b << shift);
    }
    __syncthreads();
  }
  const unsigned int thr = sh_prefix;
  if (tid == 0) { sh_cnt = 0u; sh_eq = 0u; }
  __syncthreads();
  const int base = e * CAPn;
  for (int i = 0; i < Tn / 256; ++i) {
    int t = tid + i * 256;
    unsigned int kk = keys[t];
    if (kk > thr) {
      unsigned int p = atomicAdd(&sh_cnt, 1u);
      ids[base + p] = t;
      oscore[base + p] = __uint_as_float(kk);
    } else if (kk == thr) {
      unsigned int p = atomicAdd(&sh_eq, 1u);
      if (p < 1024u) eqlist[p] = t;
    }
  }
  __syncthreads();
  if (tid == 0) {
    int need = CAPn - (int)sh_cnt;
    int m = (int)sh_eq; if (m > 1024) m = 1024;
    for (int j = 0; j < need; ++j) {
      int best = 1 << 30, bi = 0;
      for (int i2 = 0; i2 < m; ++i2)
        if (eqlist[i2] < best) { best = eqlist[i2]; bi = i2; }
      eqlist[bi] = 1 << 30;
      ids[base + (int)sh_cnt + j] = best;
      oscore[base + (int)sh_cnt + j] = __uint_as_float(thr);
    }
  }
}

// =====================================================================
// FAST PATH: all-bf16 GEMMs, global_load_lds + both-sides XOR swizzle,
// 1D grid with bijective XCD swizzle (grid % 8 == 0).
// =====================================================================

// GLU: H = bf16( silu(A@Wg^T + bg) * (A@Wu^T + bu) ), K = Dn
template <bool GATHER>
__global__ __launch_bounds__(256, 2) void kglu_bf(
    const unsigned short* __restrict__ X, const int* __restrict__ idsg,
    const unsigned short* __restrict__ Wg, const unsigned short* __restrict__ Wu,
    const float* __restrict__ biasg, const float* __restrict__ biasu,
    unsigned short* __restrict__ H, int N, int Mz, int MB, int NB) {
  constexpr int K = Dn;
  __shared__ alignas(16) unsigned char sA[16384];
  __shared__ alignas(16) unsigned char sB1[16384];
  __shared__ alignas(16) unsigned char sB2[16384];
  __shared__ int sIds[128];
  const int tid = threadIdx.x;
  const int nwg = gridDim.x;
  const int cpx = nwg >> 3;
  const int bid = blockIdx.x;
  const int swz = (bid & 7) * cpx + (bid >> 3);
  const int bm = swz % MB;
  const int bn = (swz / MB) % NB;
  const int z  = swz / (MB * NB);
  const int lane = tid & 63, w = tid >> 6;
  const int wm = w >> 1, wn = w & 1;
  const int lrow = lane & 15, lk = lane >> 4;
  const int row0 = bm * 128;

  if (tid < 128) sIds[tid] = GATHER ? idsg[z * CAPn + row0 + tid] : (row0 + tid);
  __syncthreads();

  // per-lane staging source addresses (pre-swizzled chunk so LDS ends up XOR-swizzled)
  const int lr = lane >> 3;                 // row within an 8-row issue
  const int lc = lane & 7;                  // linear LDS chunk slot this lane fills
  const int srcb = ((lc ^ lr) << 4);        // source byte offset within the 128B row
  const unsigned char* Xb = (const unsigned char*)X;
  const unsigned char* Gb = (const unsigned char*)Wg + (size_t)z * N * (K * 2);
  const unsigned char* Ub = (const unsigned char*)Wu + (size_t)z * N * (K * 2);
  const unsigned char* aP[4];
#pragma unroll
  for (int i = 0; i < 4; ++i) {
    int ar = w * 32 + 8 * i + lr;
    aP[i] = Xb + (size_t)sIds[ar] * (K * 2) + srcb;
  }
  const int br0 = bn * 128 + w * 32 + lr;
  const unsigned char* gP0 = Gb + (size_t)br0 * (K * 2) + srcb;
  const unsigned char* uP0 = Ub + (size_t)br0 * (K * 2) + srcb;

  f32x4 accG[4][4], accU[4][4];
#pragma unroll
  for (int m = 0; m < 4; ++m)
#pragma unroll
    for (int n = 0; n < 4; ++n) {
      accG[m][n] = {0.f, 0.f, 0.f, 0.f};
      accU[m][n] = {0.f, 0.f, 0.f, 0.f};
    }

  for (int k0b = 0; k0b < K * 2; k0b += 128) {
    __syncthreads();
#pragma unroll
    for (int i = 0; i < 4; ++i) {
      unsigned ldsoff = (unsigned)(w * 32 + 8 * i) * 128u;
      gload16(aP[i] + k0b, sA + ldsoff);
      gload16(gP0 + (size_t)i * 8 * (K * 2) + k0b, sB1 + ldsoff);
      gload16(uP0 + (size_t)i * 8 * (K * 2) + k0b, sB2 + ldsoff);
    }
    __syncthreads();
#pragma unroll
    for (int ks = 0; ks < 2; ++ks) {
      const int swb = (((ks * 4 + lk) ^ (lrow & 7)) << 4);
      bf16x8 av[4], gv[4], uv[4];
#pragma unroll
      for (int m = 0; m < 4; ++m)
        av[m] = *(const bf16x8*)(sA + (wm * 64 + m * 16 + lrow) * 128 + swb);
#pragma unroll
      for (int n = 0; n < 4; ++n) {
        gv[n] = *(const bf16x8*)(sB1 + (wn * 64 + n * 16 + lrow) * 128 + swb);
        uv[n] = *(const bf16x8*)(sB2 + (wn * 64 + n * 16 + lrow) * 128 + swb);
      }
#pragma unroll
      for (int m = 0; m < 4; ++m)
#pragma unroll
        for (int n = 0; n < 4; ++n) {
          accG[m][n] = __builtin_amdgcn_mfma_f32_16x16x32_bf16(av[m], gv[n], accG[m][n], 0, 0, 0);
          accU[m][n] = __builtin_amdgcn_mfma_f32_16x16x32_bf16(av[m], uv[n], accU[m][n], 0, 0, 0);
        }
    }
  }
#pragma unroll
  for (int n = 0; n < 4; ++n) {
    int col = bn * 128 + wn * 64 + n * 16 + lrow;
    float bg = biasg ? biasg[(size_t)z * N + col] : 0.f;
    float bu = biasu ? biasu[(size_t)z * N + col] : 0.f;
#pragma unroll
    for (int m = 0; m < 4; ++m) {
#pragma unroll
      for (int j = 0; j < 4; ++j) {
        float g = accG[m][n][j] + bg;
        float u = accU[m][n][j] + bu;
        float h = g / (1.f + __expf(-g)) * u;
        int row = row0 + wm * 64 + m * 16 + lk * 4 + j;
        H[(size_t)z * Mz * N + (size_t)row * N + col] = f2bf(h);
      }
    }
  }
}

// down: Out = A@W^T (+bias, xscore scatter-add when SCATTER), N = Dn
template <int K, bool SCATTER>
__global__ __launch_bounds__(256, 2) void kdown_bf(
    const unsigned short* __restrict__ Hin, const unsigned short* __restrict__ W,
    const float* __restrict__ bias, const int* __restrict__ idsg,
    const float* __restrict__ scg, float* __restrict__ Out, int Mz, int MB, int NB) {
  constexpr int N = Dn;
  __shared__ alignas(16) unsigned char sA[16384];
  __shared__ alignas(16) unsigned char sB[16384];
  __shared__ int sIds[128];
  __shared__ float sSc[128];
  const int tid = threadIdx.x;
  const int nwg = gridDim.x;
  const int cpx = nwg >> 3;
  const int bid = blockIdx.x;
  const int swz = (bid & 7) * cpx + (bid >> 3);
  const int bm = swz % MB;
  const int bn = (swz / MB) % NB;
  const int z  = swz / (MB * NB);
  const int lane = tid & 63, w = tid >> 6;
  const int wm = w >> 1, wn = w & 1;
  const int lrow = lane & 15, lk = lane >> 4;
  const int row0 = bm * 128;

  if (SCATTER && tid < 128) {
    sIds[tid] = idsg[z * CAPn + row0 + tid];
    sSc[tid] = scg[z * CAPn + row0 + tid];
  }
  __syncthreads();

  const int lr = lane >> 3;
  const int lc = lane & 7;
  const int srcb = ((lc ^ lr) << 4);
  const unsigned char* Ab = (const unsigned char*)Hin + (size_t)z * Mz * (K * 2);
  const unsigned char* Wb = (const unsigned char*)W + (size_t)z * N * (K * 2);
  const int ar0 = row0 + w * 32 + lr;
  const int br0 = bn * 128 + w * 32 + lr;
  const unsigned char* aP0 = Ab + (size_t)ar0 * (K * 2) + srcb;
  const unsigned char* bP0 = Wb + (size_t)br0 * (K * 2) + srcb;

  f32x4 acc[4][4];
#pragma unroll
  for (int m = 0; m < 4; ++m)
#pragma unroll
    for (int n = 0; n < 4; ++n) acc[m][n] = {0.f, 0.f, 0.f, 0.f};

  for (int k0b = 0; k0b < K * 2; k0b += 128) {
    __syncthreads();
#pragma unroll
    for (int i = 0; i < 4; ++i) {
      unsigned ldsoff = (unsigned)(w * 32 + 8 * i) * 128u;
      gload16(aP0 + (size_t)i * 8 * (K * 2) + k0b, sA + ldsoff);
      gload16(bP0 + (size_t)i * 8 * (K * 2) + k0b, sB + ldsoff);
    }
    __syncthreads();
#pragma unroll
    for (int ks = 0; ks < 2; ++ks) {
      const int swb = (((ks * 4 + lk) ^ (lrow & 7)) << 4);
      bf16x8 av[4], bv[4];
#pragma unroll
      for (int m = 0; m < 4; ++m)
        av[m] = *(const bf16x8*)(sA + (wm * 64 + m * 16 + lrow) * 128 + swb);
#pragma unroll
      for (int n = 0; n < 4; ++n)
        bv[n] = *(const bf16x8*)(sB + (wn * 64 + n * 16 + lrow) * 128 + swb);
#pragma unroll
      for (int m = 0; m < 4; ++m)
#pragma unroll
        for (int n = 0; n < 4; ++n)
          acc[m][n] = __builtin_amdgcn_mfma_f32_16x16x32_bf16(av[m], bv[n], acc[m][n], 0, 0, 0);
    }
  }
#pragma unroll
  for (int n = 0; n < 4; ++n) {
    int col = bn * 128 + wn * 64 + n * 16 + lrow;
    float bvv = bias ? bias[(size_t)z * N + col] : 0.f;
#pragma unroll
    for (int m = 0; m < 4; ++m) {
#pragma unroll
      for (int j = 0; j < 4; ++j) {
        int rl = wm * 64 + m * 16 + lk * 4 + j;
        float v = acc[m][n][j] + bvv;
        if (SCATTER) {
          atomicAdd(Out + (size_t)sIds[rl] * Dn + col, sSc[rl] * v);
        } else {
          Out[(size_t)(row0 + rl) * Dn + col] = v;
        }
      }
    }
  }
}

// =====================================================================
// FALLBACK PATH (round-1 kernels): fp32 weights converted on the fly.
// =====================================================================

__global__ __launch_bounds__(256, 2) void kglu(
    const unsigned short* __restrict__ X, const int* __restrict__ idsg,
    const float* __restrict__ Wg, const float* __restrict__ Wu,
    const float* __restrict__ biasg, const float* __restrict__ biasu,
    unsigned short* __restrict__ H, int N, int Mz) {
  constexpr int K = Dn;
  const int tid = threadIdx.x;
  const int bm = blockIdx.x, bn = blockIdx.y, z = blockIdx.z;
  const int lane = tid & 63, wid = tid >> 6;
  const int wm = wid >> 1, wn = wid & 1;
  const int lrow = lane & 15, lk = lane >> 4;
  __shared__ alignas(16) unsigned char sA[16384];
  __shared__ alignas(16) unsigned char sB1[16384];
  __shared__ alignas(16) unsigned char sB2[16384];
  __shared__ int sIds[128];
  const int row0 = bm * 128;
  if (tid < 128) sIds[tid] = idsg ? idsg[z * CAPn + row0 + tid] : (row0 + tid);
  const float* wgp = Wg + (size_t)z * N * K;
  const float* wup = Wu + (size_t)z * N * K;
  f32x4 accG[4][4], accU[4][4];
#pragma unroll
  for (int m = 0; m < 4; ++m)
#pragma unroll
    for (int n = 0; n < 4; ++n) {
      accG[m][n] = {0.f, 0.f, 0.f, 0.f};
      accU[m][n] = {0.f, 0.f, 0.f, 0.f};
    }
  for (int k0 = 0; k0 < K; k0 += 64) {
    __syncthreads();
#pragma unroll
    for (int i = 0; i < 4; ++i) {
      int c = tid + i * 256;
      int r = c >> 3, ch = c & 7;
      int dst = r * 128 + ((ch ^ (r & 7)) << 4);
      uint4 va = *(const uint4*)(X + (size_t)sIds[r] * K + (k0 + ch * 8));
      *(uint4*)(sA + dst) = va;
      const float* pg = wgp + (size_t)(bn * 128 + r) * K + (k0 + ch * 8);
      float4 g0 = *(const float4*)pg, g1 = *(const float4*)(pg + 4);
      uint4 ug = { pack2(g0.x, g0.y), pack2(g0.z, g0.w), pack2(g1.x, g1.y), pack2(g1.z, g1.w) };
      *(uint4*)(sB1 + dst) = ug;
      const float* pu = wup + (size_t)(bn * 128 + r) * K + (k0 + ch * 8);
      float4 u0 = *(const float4*)pu, u1 = *(const float4*)(pu + 4);
      uint4 uu = { pack2(u0.x, u0.y), pack2(u0.z, u0.w), pack2(u1.x, u1.y), pack2(u1.z, u1.w) };
      *(uint4*)(sB2 + dst) = uu;
    }
    __syncthreads();
#pragma unroll
    for (int ks = 0; ks < 2; ++ks) {
      const int sw = ((ks * 4 + lk) ^ (lrow & 7)) << 4;
      bf16x8 av[4], gv[4], uv[4];
#pragma unroll
      for (int m = 0; m < 4; ++m)
        av[m] = *(const bf16x8*)(sA + (wm * 64 + m * 16 + lrow) * 128 + sw);
#pragma unroll
      for (int n = 0; n < 4; ++n) {
        gv[n] = *(const bf16x8*)(sB1 + (wn * 64 + n * 16 + lrow) * 128 + sw);
        uv[n] = *(const bf16x8*)(sB2 + (wn * 64 + n * 16 + lrow) * 128 + sw);
      }
#pragma unroll
      for (int m = 0; m < 4; ++m)
#pragma unroll
        for (int n = 0; n < 4; ++n) {
          accG[m][n] = __builtin_amdgcn_mfma_f32_16x16x32_bf16(av[m], gv[n], accG[m][n], 0, 0, 0);
          accU[m][n] = __builtin_amdgcn_mfma_f32_16x16x32_bf16(av[m], uv[n], accU[m][n], 0, 0, 0);
        }
    }
  }
#pragma unroll
  for (int n = 0; n < 4; ++n) {
    int col = bn * 128 + wn * 64 + n * 16 + lrow;
    float bg = biasg ? biasg[(size_t)z * N + col] : 0.f;
    float bu = biasu ? biasu[(size_t)z * N + col] : 0.f;
#pragma unroll
    for (int m = 0; m < 4; ++m) {
#pragma unroll
      for (int j = 0; j < 4; ++j) {
        float g = accG[m][n][j] + bg;
        float u = accU[m][n][j] + bu;
        float h = g / (1.f + __expf(-g)) * u;
        int row = row0 + wm * 64 + m * 16 + lk * 4 + j;
        H[(size_t)z * Mz * N + (size_t)row * N + col] = f2bf(h);
      }
    }
  }
}

template <int K>
__global__ __launch_bounds__(256, 2) void kdown(
    const unsigned short* __restrict__ Hin, const float* __restrict__ W,
    const float* __restrict__ bias, const int* __restrict__ idsg,
    const float* __restrict__ scg, float* __restrict__ Out, int Mz) {
  constexpr int N = Dn;
  const int tid = threadIdx.x;
  const int bm = blockIdx.x, bn = blockIdx.y, z = blockIdx.z;
  const int lane = tid & 63, wid = tid >> 6;
  const int wm = wid >> 1, wn = wid & 1;
  const int lrow = lane & 15, lk = lane >> 4;
  __shared__ alignas(16) unsigned char sA[16384];
  __shared__ alignas(16) unsigned char sB[16384];
  __shared__ int sIds[128];
  __shared__ float sSc[128];
  const int row0 = bm * 128;
  if (idsg && tid < 128) {
    sIds[tid] = idsg[z * CAPn + row0 + tid];
    sSc[tid] = scg[z * CAPn + row0 + tid];
  }
  const unsigned short* A = Hin + (size_t)z * Mz * K;
  const float* wp = W + (size_t)z * N * K;
  f32x4 acc[4][4];
#pragma unroll
  for (int m = 0; m < 4; ++m)
#pragma unroll
    for (int n = 0; n < 4; ++n) acc[m][n] = {0.f, 0.f, 0.f, 0.f};
  for (int k0 = 0; k0 < K; k0 += 64) {
    __syncthreads();
#pragma unroll
    for (int i = 0; i < 4; ++i) {
      int c = tid + i * 256;
      int r = c >> 3, ch = c & 7;
      int dst = r * 128 + ((ch ^ (r & 7)) << 4);
      uint4 va = *(const uint4*)(A + (size_t)(row0 + r) * K + (k0 + ch * 8));
      *(uint4*)(sA + dst) = va;
      const float* pb = wp + (size_t)(bn * 128 + r) * K + (k0 + ch * 8);
      float4 b0 = *(const float4*)pb, b1 = *(const float4*)(pb + 4);
      uint4 ub = { pack2(b0.x, b0.y), pack2(b0.z, b0.w), pack2(b1.x, b1.y), pack2(b1.z, b1.w) };
      *(uint4*)(sB + dst) = ub;
    }
    __syncthreads();
#pragma unroll
    for (int ks = 0; ks < 2; ++ks) {
      const int sw = ((ks * 4 + lk) ^ (lrow & 7)) << 4;
      bf16x8 av[4], bv[4];
#pragma unroll
      for (int m = 0; m < 4; ++m)
        av[m] = *(const bf16x8*)(sA + (wm * 64 + m * 16 + lrow) * 128 + sw);
#pragma unroll
      for (int n = 0; n < 4; ++n)
        bv[n] = *(const bf16x8*)(sB + (wn * 64 + n * 16 + lrow) * 128 + sw);
#pragma unroll
      for (int m = 0; m < 4; ++m)
#pragma unroll
        for (int n = 0; n < 4; ++n)
          acc[m][n] = __builtin_amdgcn_mfma_f32_16x16x32_bf16(av[m], bv[n], acc[m][n], 0, 0, 0);
    }
  }
#pragma unroll
  for (int n = 0; n < 4; ++n) {
    int col = bn * 128 + wn * 64 + n * 16 + lrow;
    float bvv = bias ? bias[(size_t)z * N + col] : 0.f;
#pragma unroll
    for (int m = 0; m < 4; ++m) {
#pragma unroll
      for (int j = 0; j < 4; ++j) {
        int rl = wm * 64 + m * 16 + lk * 4 + j;
        float v = acc[m][n][j] + bvv;
        if (idsg) {
          atomicAdd(Out + (size_t)sIds[rl] * Dn + col, sSc[rl] * v);
        } else {
          Out[(size_t)(row0 + rl) * Dn + col] = v;
        }
      }
    }
  }
}

extern "C" void kernel_launch(void* const* d_in, const int* in_sizes, int n_in,
                              void* d_out, int out_size, void* d_ws, size_t ws_size,
                              hipStream_t stream) {
  const float* x      = (const float*)d_in[0];
  const float* gate_w = (const float*)d_in[1];
  const float* up_w   = (const float*)d_in[2];
  const float* up_b   = (const float*)d_in[3];
  const float* gw     = (const float*)d_in[4];
  const float* gb     = (const float*)d_in[5];
  const float* down_w = (const float*)d_in[6];
  const float* down_b = (const float*)d_in[7];
  const float* shg    = (const float*)d_in[8];
  const float* shu    = (const float*)d_in[9];
  const float* shd    = (const float*)d_in[10];
  float* out = (float*)d_out;

  const size_t H_BYTES  = (size_t)En * CAPn * Fn * 2;   // 134 MiB
  const size_t XB_BYTES = (size_t)Tn * Dn * 2;          // 16 MiB
  const size_t WE_BYTES = (size_t)En * Fn * Dn * 2;     // 128 MiB (per expert weight tensor)
  const size_t SH_BYTES = (size_t)SHn * Dn * 2;         // 4 MiB
  const size_t SC_BYTES = (size_t)En * Tn * 4;
  const size_t ID_BYTES = (size_t)En * CAPn * 4;

  const size_t fast_need = H_BYTES + XB_BYTES + 3 * WE_BYTES + 3 * SH_BYTES +
                           SC_BYTES + 2 * ID_BYTES;
  const size_t slow_need = H_BYTES + XB_BYTES + SC_BYTES + 2 * ID_BYTES;

  char* ws = (char*)d_ws;

  if (ws_size >= fast_need) {
    // ---------------- fast path ----------------
    char* p = ws;
    unsigned short* H   = (unsigned short*)p; p += H_BYTES;
    unsigned short* xb  = (unsigned short*)p; p += XB_BYTES;
    unsigned short* upb = (unsigned short*)p; p += WE_BYTES;
    unsigned short* gwb = (unsigned short*)p; p += WE_BYTES;
    unsigned short* dwb = (unsigned short*)p; p += WE_BYTES;
    unsigned short* shgb = (unsigned short*)p; p += SH_BYTES;
    unsigned short* shub = (unsigned short*)p; p += SH_BYTES;
    unsigned short* shdb = (unsigned short*)p; p += SH_BYTES;
    float* scores = (float*)p; p += SC_BYTES;
    int* ids      = (int*)p;  p += ID_BYTES;
    float* osc    = (float*)p;

    kcvt<<<2048, 256, 0, stream>>>(x, xb, Tn * Dn / 8);
    kscores<<<Tn, 256, 0, stream>>>(x, gate_w, scores);
    kselect<<<En, 256, 0, stream>>>(scores, ids, osc);
    kcvt<<<2048, 256, 0, stream>>>(up_w, upb, En * Fn * Dn / 8);
    kcvt<<<2048, 256, 0, stream>>>(gw, gwb, En * Fn * Dn / 8);
    kcvt<<<2048, 256, 0, stream>>>(down_w, dwb, En * Dn * Fn / 8);
    kcvt<<<256, 256, 0, stream>>>(shg, shgb, SHn * Dn / 8);
    kcvt<<<256, 256, 0, stream>>>(shu, shub, SHn * Dn / 8);
    kcvt<<<256, 256, 0, stream>>>(shd, shdb, Dn * SHn / 8);

    // shared dense GLU MLP (writes every element of d_out)
    kglu_bf<false><<<(Tn / 128) * (SHn / 128), 256, 0, stream>>>(
        xb, nullptr, shgb, shub, nullptr, nullptr, H, SHn, Tn, Tn / 128, SHn / 128);
    kdown_bf<SHn, false><<<(Tn / 128) * (Dn / 128), 256, 0, stream>>>(
        H, shdb, nullptr, nullptr, nullptr, out, Tn, Tn / 128, Dn / 128);

    // expert path (atomic scatter-add on top)
    kglu_bf<true><<<(CAPn / 128) * (Fn / 128) * En, 256, 0, stream>>>(
        xb, ids, gwb, upb, gb, up_b, H, Fn, CAPn, CAPn / 128, Fn / 128);
    kdown_bf<Fn, true><<<(CAPn / 128) * (Dn / 128) * En, 256, 0, stream>>>(
        H, dwb, down_b, ids, osc, out, CAPn, CAPn / 128, Dn / 128);
    return;
  }

  if (ws_size < slow_need) return;
  // ---------------- fallback (round-1) path ----------------
  unsigned short* H  = (unsigned short*)ws;
  unsigned short* xb = (unsigned short*)(ws + H_BYTES);
  float* scores      = (float*)(ws + H_BYTES + XB_BYTES);
  int* ids           = (int*)(ws + H_BYTES + XB_BYTES + SC_BYTES);
  float* osc         = (float*)(ws + H_BYTES + XB_BYTES + SC_BYTES + ID_BYTES);

  kcvt<<<2048, 256, 0, stream>>>(x, xb, Tn * Dn / 8);
  kscores<<<Tn, 256, 0, stream>>>(x, gate_w, scores);
  kselect<<<En, 256, 0, stream>>>(scores, ids, osc);

  kglu<<<dim3(Tn / 128, SHn / 128, 1), 256, 0, stream>>>(
      xb, nullptr, shg, shu, nullptr, nullptr, H, SHn, Tn);
  kdown<SHn><<<dim3(Tn / 128, Dn / 128, 1), 256, 0, stream>>>(
      H, shd, nullptr, nullptr, nullptr, out, Tn);

  kglu<<<dim3(CAPn / 128, Fn / 128, En), 256, 0, stream>>>(
      xb, ids, gw, up_w, gb, up_b, H, Fn, CAPn);
  kdown<Fn><<<dim3(CAPn / 128, Dn / 128, En), 256, 0, stream>>>(
      H, down_w, down_b, ids, osc, out, CAPn);
}